// Round 3
// baseline (3921.534 us; speedup 1.0000x reference)
//
#include <hip/hip_runtime.h>
#include <cstdint>
#include <cstddef>

#define NN 32
#define NODE_ELEMS 1605632  // 8*64*56*56

typedef unsigned __int128 u128;

// ---------------- host: replicate np.random.default_rng(0).random((32,32)) < 0.25 ----
static void compute_adj(bool adj[NN][NN]) {
  // SeedSequence(0): pool of 4, entropy=[0]
  uint32_t pool[4];
  uint32_t hc = 0x43b0d7e5u;
  auto hashmix = [&hc](uint32_t v) -> uint32_t {
    v ^= hc; hc *= 0x931e8875u; v *= hc; v ^= v >> 16; return v;
  };
  auto mix = [](uint32_t x, uint32_t y) -> uint32_t {
    uint32_t r = x * 0xca01f9ddu - y * 0x4973f715u; r ^= r >> 16; return r;
  };
  for (int i = 0; i < 4; i++) pool[i] = hashmix(0u);  // entropy word 0 then run-out
  for (int s = 0; s < 4; s++)
    for (int d = 0; d < 4; d++)
      if (s != d) pool[d] = mix(pool[d], hashmix(pool[s]));
  // generate_state(4, uint64) -> 8x uint32, little-endian pairs
  uint32_t hb = 0x8b51f9ddu;
  uint32_t w[8];
  for (int k = 0; k < 8; k++) {
    uint32_t v = pool[k & 3];
    v ^= hb; hb *= 0x58f38dedu; v *= hb; v ^= v >> 16;
    w[k] = v;
  }
  uint64_t s64[4];
  for (int j = 0; j < 4; j++) s64[j] = (uint64_t)w[2 * j] | ((uint64_t)w[2 * j + 1] << 32);
  u128 initstate = ((u128)s64[0] << 64) | s64[1];   // seed[0]=high
  u128 initseq   = ((u128)s64[2] << 64) | s64[3];
  const u128 MULT = ((u128)0x2360ED051FC65DA4ULL << 64) | 0x4385DF649FCCF645ULL;
  u128 state = 0;
  u128 inc = (initseq << 1) | 1;
  state = state * MULT + inc;   // srandom: step
  state += initstate;
  state = state * MULT + inc;   // step
  for (int i = 0; i < NN; i++)
    for (int j = 0; j < NN; j++) {
      state = state * MULT + inc;  // step-then-output (128-bit variant)
      uint64_t hi = (uint64_t)(state >> 64), lo = (uint64_t)state;
      unsigned rot = (unsigned)(hi >> 58);
      uint64_t xr = hi ^ lo;
      uint64_t out = (xr >> rot) | (xr << ((64u - rot) & 63u));
      double dv = (double)(out >> 11) * (1.0 / 9007199254740992.0);
      adj[i][j] = (dv < 0.25);
    }
}

// ---------------- device ----------------
struct NodeDesc {
  uint8_t node, npred, slot, flags;  // flags bit0: accumulate into d_out
  uint8_t pred_slot[31];
  uint8_t pad;
};
struct GroupArg { int n; NodeDesc d[16]; };

__global__ __launch_bounds__(256) void node_kernel(
    GroupArg g,
    const float* __restrict__ x,
    const float* __restrict__ dwall,
    const float* __restrict__ pwall,
    const float* __restrict__ gmall,
    const float* __restrict__ btall,
    const float* __restrict__ mnall,
    const float* __restrict__ vrall,
    const float* __restrict__ aggw,
    float* __restrict__ ws,
    float* __restrict__ dout,
    float inv_nf)
{
  __shared__ float smem[8192];   // union: y-halo [64][100] (6400) | t [64][64] (4096) + pw_swz (4096)
  __shared__ float wlds[32];

  const NodeDesc nd = g.d[blockIdx.y];
  const int node = nd.node;
  const int t = threadIdx.x;
  const int b = blockIdx.x / 49;
  const int tile = blockIdx.x - b * 49;
  const int ty = (tile / 7) * 8;
  const int tx = (tile % 7) * 8;

  const int c_dw = t >> 2;   // depthwise: channel per 4 threads
  const int pg = t & 3;      // position group of 16

  // depthwise weights for this thread's channel
  const float* k9 = dwall + (node * 64 + c_dw) * 9;
  float kk[9];
  #pragma unroll
  for (int q = 0; q < 9; q++) kk[q] = k9[q];

  float tv[16];  // depthwise outputs (positions pg*16 .. pg*16+15)

  if (nd.npred == 0) {
    // ---- input node: depthwise stride-2 over relu(x), x is [8][64][112][112]
    const float* xb = x + (size_t)(b * 64 + c_dw) * 12544;
    #pragma unroll
    for (int j = 0; j < 16; j++) {
      int p = pg * 16 + j;
      int oy = ty + (p >> 3), ox = tx + (p & 7);
      int iy0 = oy * 2 - 1, ix0 = ox * 2 - 1;
      float s = 0.f;
      #pragma unroll
      for (int dy = 0; dy < 3; dy++) {
        int iy = iy0 + dy;
        if ((unsigned)iy >= 112u) continue;
        const float* row = xb + iy * 112;
        #pragma unroll
        for (int dx = 0; dx < 3; dx++) {
          int ix = ix0 + dx;
          if ((unsigned)ix >= 112u) continue;
          s += fmaxf(row[ix], 0.f) * kk[dy * 3 + dx];
        }
      }
      tv[j] = s;
    }
  } else {
    // ---- aggregation weights: sigmoid ONLY for >=2 preds; single pred is a
    //      plain pass-through in the reference (R2 bug: we weighted it too)
    if (t < nd.npred) {
      float wv = 1.f / (1.f + expf(-aggw[node * 32 + t]));
      wlds[t] = (nd.npred == 1) ? 1.0f : wv;
    }
    __syncthreads();
    const int np = nd.npred;
    // ---- aggregate + relu into y-halo LDS [64][10][10]
    for (int idx = t; idx < 6400; idx += 256) {
      int c = idx / 100;
      int r = idx - c * 100;
      int iy = r / 10, ix = r - iy * 10;
      int gy = ty + iy - 1, gx = tx + ix - 1;
      float v = 0.f;
      if ((unsigned)gy < 56u && (unsigned)gx < 56u) {
        int off = ((b * 64 + c) * 56 + gy) * 56 + gx;
        float s = 0.f;
        for (int p = 0; p < np; p++) {
          const float* pr = ws + (size_t)nd.pred_slot[p] * NODE_ELEMS;
          s += wlds[p] * pr[off];
        }
        v = fmaxf(s, 0.f);
      }
      smem[idx] = v;
    }
    __syncthreads();
    // ---- depthwise 3x3 stride 1 from LDS halo
    const float* yb = smem + c_dw * 100;
    #pragma unroll
    for (int j = 0; j < 16; j++) {
      int p = pg * 16 + j;
      int py = p >> 3, px = p & 7;
      const float* r = yb + py * 10 + px;
      tv[j] = r[0] * kk[0] + r[1] * kk[1] + r[2] * kk[2]
            + r[10] * kk[3] + r[11] * kk[4] + r[12] * kk[5]
            + r[20] * kk[6] + r[21] * kk[7] + r[22] * kk[8];
    }
  }

  __syncthreads();  // all reads of y-halo done; smem is now re-purposed

  // ---- write t matrix [k=c][pos]; stage pw with QUAD-granular XOR swizzle:
  //      element (c,k) lives at c*64 + (((k>>2) ^ (c&15))<<2) + (k&3)
  //      -> float4 reads are 16B-aligned and never wrap
  #pragma unroll
  for (int j4 = 0; j4 < 4; j4++) {
    float4 v = make_float4(tv[j4 * 4 + 0], tv[j4 * 4 + 1], tv[j4 * 4 + 2], tv[j4 * 4 + 3]);
    *(float4*)&smem[c_dw * 64 + pg * 16 + j4 * 4] = v;
  }
  {
    const float* pwn = pwall + node * 4096;
    #pragma unroll
    for (int i = 0; i < 16; i++) {
      int gidx = t + 256 * i;
      int c = gidx >> 6, k = gidx & 63;
      smem[4096 + c * 64 + ((((k >> 2) ^ (c & 15)) << 2) | (k & 3))] = pwn[gidx];
    }
  }
  __syncthreads();

  // ---- pointwise 64x64: 4 out-channels x 4 positions per thread
  const int c0 = (t >> 4) << 2;
  const int pos0 = (t & 15) << 2;
  float acc[4][4] = {};
  const float* tl = smem;
  const float* pl = smem + 4096;
  #pragma unroll
  for (int k4 = 0; k4 < 16; k4++) {
    const int k = k4 * 4;
    float4 A4[4];
    #pragma unroll
    for (int ci = 0; ci < 4; ci++) {
      int c = c0 + ci;
      A4[ci] = *(const float4*)&pl[c * 64 + ((k4 ^ (c & 15)) << 2)];
    }
    float Bf[4][4];
    #pragma unroll
    for (int kq = 0; kq < 4; kq++) {
      float4 v = *(const float4*)&tl[(k + kq) * 64 + pos0];
      Bf[kq][0] = v.x; Bf[kq][1] = v.y; Bf[kq][2] = v.z; Bf[kq][3] = v.w;
    }
    #pragma unroll
    for (int ci = 0; ci < 4; ci++) {
      float aa[4] = {A4[ci].x, A4[ci].y, A4[ci].z, A4[ci].w};
      #pragma unroll
      for (int kq = 0; kq < 4; kq++) {
        #pragma unroll
        for (int pj = 0; pj < 4; pj++)
          acc[ci][pj] = fmaf(aa[kq], Bf[kq][pj], acc[ci][pj]);
      }
    }
  }

  // ---- BN + stores
  const int py = pos0 >> 3;
  const int px = pos0 & 7;  // {0,4}
  const int oy = ty + py, ox = tx + px;
  float* slotp = (nd.slot != 255) ? (ws + (size_t)nd.slot * NODE_ELEMS) : nullptr;
  #pragma unroll
  for (int ci = 0; ci < 4; ci++) {
    int c = c0 + ci;
    int gi = node * 64 + c;
    float inv = gmall[gi] / sqrtf(vrall[gi] + 1e-5f);
    float mn = mnall[gi], bt = btall[gi];
    size_t off = (((size_t)b * 64 + c) * 56 + oy) * 56 + ox;
    float o0 = (acc[ci][0] - mn) * inv + bt;
    float o1 = (acc[ci][1] - mn) * inv + bt;
    float o2 = (acc[ci][2] - mn) * inv + bt;
    float o3 = (acc[ci][3] - mn) * inv + bt;
    if (slotp) {
      float4 v = make_float4(o0, o1, o2, o3);
      *(float4*)&slotp[off] = v;
    }
    if (nd.flags & 1) {
      atomicAdd(&dout[off + 0], o0 * inv_nf);
      atomicAdd(&dout[off + 1], o1 * inv_nf);
      atomicAdd(&dout[off + 2], o2 * inv_nf);
      atomicAdd(&dout[off + 3], o3 * inv_nf);
    }
  }
}

// ---------------- launcher ----------------
extern "C" void kernel_launch(void* const* d_in, const int* in_sizes, int n_in,
                              void* d_out, int out_size, void* d_ws, size_t ws_size,
                              hipStream_t stream) {
  (void)in_sizes; (void)n_in; (void)ws_size;
  const float* x     = (const float*)d_in[0];
  const float* dw    = (const float*)d_in[1];
  const float* pw    = (const float*)d_in[2];
  const float* gamma = (const float*)d_in[3];
  const float* beta  = (const float*)d_in[4];
  const float* mean  = (const float*)d_in[5];
  const float* var   = (const float*)d_in[6];
  const float* aggw  = (const float*)d_in[7];
  float* ws = (float*)d_ws;
  float* out = (float*)d_out;

  bool adj[NN][NN];
  compute_adj(adj);

  int npred[NN], preds[NN][NN], nsucc[NN], ispan[NN], level[NN];
  for (int j = 0; j < NN; j++) {
    npred[j] = 0;
    for (int i = 0; i < j; i++) if (adj[i][j]) preds[j][npred[j]++] = i;
  }
  for (int i = 0; i < NN; i++) {
    nsucc[i] = 0; ispan[i] = NN;
    int mx = -1;
    for (int j = i + 1; j < NN; j++) if (adj[i][j]) { nsucc[i]++; mx = j; }
    if (nsucc[i] > 0) ispan[i] = mx;
  }
  int maxlev = 0;
  for (int j = 0; j < NN; j++) {
    int lv = 0;
    for (int p = 0; p < npred[j]; p++) {
      int cand = level[preds[j][p]] + 1;
      if (cand > lv) lv = cand;
    }
    level[j] = lv;
    if (lv > maxlev) maxlev = lv;
  }
  bool isfinal[NN]; int nf = 0;
  for (int i = 0; i < NN; i++) { isfinal[i] = (ispan[i] >= NN - 1); if (isfinal[i]) nf++; }
  // last consumer level of each producer
  int lastlvl[NN];
  for (int i = 0; i < NN; i++) {
    lastlvl[i] = -1;
    for (int j = i + 1; j < NN; j++) if (adj[i][j] && level[j] > lastlvl[i]) lastlvl[i] = level[j];
  }
  // greedy slot allocation in level order; frees strictly after same-level allocs
  int slot[NN]; bool used[NN];
  for (int s = 0; s < NN; s++) used[s] = false;
  for (int L = 0; L <= maxlev; L++) {
    for (int i = 0; i < NN; i++) {
      if (level[i] != L) continue;
      if (nsucc[i] > 0) {
        int s = 0; while (used[s]) s++;
        used[s] = true; slot[i] = s;
      } else slot[i] = 255;
    }
    for (int i = 0; i < NN; i++)
      if (level[i] < L + 1 && slot[i] != 255 && lastlvl[i] == L && nsucc[i] > 0)
        used[slot[i]] = false;
  }

  hipMemsetAsync(d_out, 0, (size_t)out_size * sizeof(float), stream);
  float inv_nf = 1.0f / (float)nf;

  for (int L = 0; L <= maxlev; L++) {
    GroupArg g; g.n = 0;
    for (int i = 0; i < NN; i++) {
      if (level[i] != L) continue;
      NodeDesc& nd = g.d[g.n++];
      nd.node = (uint8_t)i;
      nd.npred = (uint8_t)npred[i];
      nd.slot = (uint8_t)slot[i];
      nd.flags = isfinal[i] ? 1 : 0;
      for (int p = 0; p < npred[i]; p++) nd.pred_slot[p] = (uint8_t)slot[preds[i][p]];
      if (g.n == 16) {
        node_kernel<<<dim3(392, g.n), 256, 0, stream>>>(g, x, dw, pw, gamma, beta,
                                                        mean, var, aggw, ws, out, inv_nf);
        g.n = 0;
      }
    }
    if (g.n > 0) {
      node_kernel<<<dim3(392, g.n), 256, 0, stream>>>(g, x, dw, pw, gamma, beta,
                                                      mean, var, aggw, ws, out, inv_nf);
    }
  }
}